// Round 1
// 147.168 us; speedup vs baseline: 1.0040x; 1.0040x over previous
//
#include <hip/hip_runtime.h>
#include <math.h>

// AntiAliasInterpolation2d: 13x13 separable gaussian (sigma=1.5, zero-pad 6)
// + nearest 4x downsample, fused. x: (32,512,512,3) f32 -> (32,128,128,3) f32.
//
// R5: BARRIER-FREE wave-private restructure. R4's 8 per-row __syncthreads each
// forced a compiler-emitted `s_waitcnt vmcnt(0)` drain of the distance-2 global
// prefetch ring (guide §5 barrier-drain), exposing HBM latency once per output
// row. Now each WAVE owns a 16-output-col segment including the 13-tap halo:
//   - loads 56 contiguous float4/row (flat [12*j0-20, 12*j0+223], planar
//     x in [4*j0-6, 4*j0+67]) -- +17% halo redundancy, L1/L2-absorbed
//   - same rolling vertical conv (quads, ring-of-3 prefetch, static pruning)
//   - scatters the blurred row into a WAVE-PRIVATE planar LDS segment
//     (3 ch x 76 floats, double-buffered)
//   - handoff is intra-wave only: `s_waitcnt lgkmcnt(0)` inline asm with
//     "memory" clobber (cross-LANE RAW is invisible to per-thread alias
//     analysis -- the fence is REQUIRED), then 3x ds_read_b128 + 1 scalar.
// Zero s_barriers in the kernel => the global-load pipe never drains.

namespace {
constexpr int N_IMG   = 32;
constexpr int H_IN    = 512;
constexpr int W_IN    = 512;
constexpr int C_CH    = 3;
constexpr int H_OUT   = 128;
constexpr int W_OUT   = 128;
constexpr int T_ROWS  = 8;                 // output rows per block
constexpr int BANDS   = H_OUT / T_ROWS;    // 16
constexpr int ROW_ELEMS = W_IN * C_CH;     // 1536
constexpr int WAVES   = 4;                 // waves per block
constexpr int NTHREADS = 64 * WAVES;       // 256
constexpr int SEG_COLS = 16;               // output cols per wave
constexpr int BLOCKS_PER_BAND = (W_OUT / SEG_COLS) / WAVES;  // 2
constexpr int SEGC    = 76;                // LDS channel-plane stride (floats)
                                           // covers x in [4j0-6, 4j0+67]+slack
constexpr int SEGPAD  = 232;               // 3*76=228 used + 4 dump/pad (16B mult)
constexpr int LDS_PER_WAVE = 2 * SEGPAD;   // double-buffered by row parity
constexpr int LDS_FLOATS   = WAVES * LDS_PER_WAVE;  // 1856 floats = 7.4 KB
}

__device__ __forceinline__ float4 f4fma(float w, const float4& p, const float4& a) {
  return make_float4(fmaf(w, p.x, a.x), fmaf(w, p.y, a.y),
                     fmaf(w, p.z, a.z), fmaf(w, p.w, a.w));
}

__global__ __launch_bounds__(NTHREADS, 3)
void aa_blur_down(const float* __restrict__ in, float* __restrict__ out) {
  __shared__ __align__(16) float lds[LDS_FLOATS];

  const int tid  = threadIdx.x;
  const int lane = tid & 63;
  const int wv   = tid >> 6;
  const int bid  = blockIdx.x;
  const int n    = bid / (BANDS * BLOCKS_PER_BAND);
  const int rr   = bid % (BANDS * BLOCKS_PER_BAND);
  const int band = rr / BLOCKS_PER_BAND;
  const int half = rr % BLOCKS_PER_BAND;
  const int i0   = band * T_ROWS;
  const int j0   = (half * WAVES + wv) * SEG_COLS;   // first output col of wave

  // normalized 1D gaussian weights (13 taps), static use -> registers
  float wt[13];
  {
    float s = 0.f;
#pragma unroll
    for (int r = 0; r < 13; ++r) {
      const float d = (float)r - 6.0f;
      wt[r] = expf(-d * d * (1.0f / 4.5f));
      s += wt[r];
    }
    const float inv = 1.0f / s;
#pragma unroll
    for (int r = 0; r < 13; ++r) wt[r] *= inv;
  }

  // wave-private LDS segment; zero both buffers once (establishes the column
  // zero-padding at the image edges -- those slots are never rewritten)
  float* const wlds = &lds[wv * LDS_PER_WAVE];
  for (int idx = lane; idx < LDS_PER_WAVE; idx += 64) wlds[idx] = 0.f;
  asm volatile("s_waitcnt lgkmcnt(0)" ::: "memory");

  // this lane's global float4: flat floats g..g+3 of each input row.
  // G0 = 12*j0 - 18 is the first needed flat (planar x = 4*j0-6); align down
  // to 12*j0 - 20 for float4. The two lead floats belong to x = 4*j0-7 (rel<0)
  // and are redirected to a dump slot.
  const int g = 12 * j0 - 20 + 4 * lane;
  const bool vload = (g >= 0) && (g < ROW_ELEMS);   // float4 fully in-row
  int offs[4];                                       // planar scatter offsets
#pragma unroll
  for (int e = 0; e < 4; ++e) {
    const int gg  = (vload ? g : 0) + e;
    const int cc  = gg % 3;
    const int xx  = gg / 3;
    const int rel = xx - (4 * j0 - 6);
    offs[e] = (rel >= 0 && rel < SEGC) ? (cc * SEGC + rel) : (3 * SEGC); // dump
  }

  const int qstart = i0 - 2;                 // quads qstart..qstart+10
  const float* img = in + (size_t)n * H_IN * ROW_ELEMS;

  // horizontal-conv role: lanes 0..47 produce out flat 3*j0 + lane
  const int  jr   = lane / 3;
  const int  ch   = lane % 3;
  const bool hact = (lane < 48);

  // row (s,m) dead pruning: s==0 rows m<2 and s==10 row m==3 feed only
  // discarded accumulators (see static conditions in the loop).
  float4 P[3][4];
  auto loadq = [&](int slot, int s) {
#pragma unroll
    for (int m = 0; m < 4; ++m) {
      const bool dead = (s == 0 && m < 2) || (s == 10 && m == 3);
      const int y = 4 * (qstart + s) + m;
      if (!dead && vload && (unsigned)y < (unsigned)H_IN) {
        P[slot][m] = *reinterpret_cast<const float4*>(img + (size_t)y * ROW_ELEMS + g);
      } else {
        P[slot][m] = make_float4(0.f, 0.f, 0.f, 0.f);
      }
    }
  };

  float4 A0 = make_float4(0,0,0,0), A1 = A0, A2 = A0, A3 = A0;

  loadq(0, 0);
  loadq(1, 1);

#pragma unroll
  for (int s = 0; s <= 10; ++s) {
    if (s + 2 <= 10) loadq((s + 2) % 3, s + 2);   // distance-2 prefetch, ring of 3

    const float4 p0 = P[s % 3][0];
    const float4 p1 = P[s % 3][1];
    const float4 p2 = P[s % 3][2];
    const float4 p3 = P[s % 3][3];

    // vertical accumulation; statically pruned to live output rows
    if (s >= 3)           { A0 = f4fma(wt[10], p0, A0); A0 = f4fma(wt[11], p1, A0); A0 = f4fma(wt[12], p2, A0); }
    if (s >= 2 && s <= 9) { A1 = f4fma(wt[6],  p0, A1); A1 = f4fma(wt[7],  p1, A1); A1 = f4fma(wt[8],  p2, A1); A1 = f4fma(wt[9], p3, A1); }
    if (s >= 1 && s <= 8) { A2 = f4fma(wt[2],  p0, A2); A2 = f4fma(wt[3],  p1, A2); A2 = f4fma(wt[4],  p2, A2); A2 = f4fma(wt[5], p3, A2); }
    if (s <= 7)           { A3 = f4fma(wt[0],  p2, A3); A3 = f4fma(wt[1],  p3, A3); }

    if (s >= 3) {
      // A0 = vertically blurred row i for this wave's segment
      const int i = i0 + s - 3;
      float* buf = wlds + ((s - 3) & 1) * SEGPAD;   // double-buffer by parity
      if (vload) {
        buf[offs[0]] = A0.x; buf[offs[1]] = A0.y;
        buf[offs[2]] = A0.z; buf[offs[3]] = A0.w;
      }
      // intra-wave handoff: cross-lane RAW through LDS. Lanes of a wave run in
      // lockstep; only the lgkm drain is needed. No s_barrier => no vmcnt(0)
      // drain of the global prefetch ring.
      asm volatile("s_waitcnt lgkmcnt(0)" ::: "memory");
      if (hact) {
        // 13-tap horizontal conv: planar window x in [4j-6, 4j+6],
        // rel = 4*jr + k, float4-aligned at rel 4*jr.
        const float* pl = buf + ch * SEGC + 4 * jr;
        const float4 wa = *reinterpret_cast<const float4*>(pl);
        const float4 wb = *reinterpret_cast<const float4*>(pl + 4);
        const float4 wc = *reinterpret_cast<const float4*>(pl + 8);
        const float  wd = pl[12];
        float hh;
        hh = wt[0] * wa.x;
        hh = fmaf(wt[1],  wa.y, hh);
        hh = fmaf(wt[2],  wa.z, hh);
        hh = fmaf(wt[3],  wa.w, hh);
        hh = fmaf(wt[4],  wb.x, hh);
        hh = fmaf(wt[5],  wb.y, hh);
        hh = fmaf(wt[6],  wb.z, hh);
        hh = fmaf(wt[7],  wb.w, hh);
        hh = fmaf(wt[8],  wc.x, hh);
        hh = fmaf(wt[9],  wc.y, hh);
        hh = fmaf(wt[10], wc.z, hh);
        hh = fmaf(wt[11], wc.w, hh);
        hh = fmaf(wt[12], wd,   hh);
        out[(size_t)(n * H_OUT + i) * (W_OUT * C_CH) + 3 * j0 + lane] = hh;
      }
    }

    A0 = A1; A1 = A2; A2 = A3; A3 = make_float4(0.f, 0.f, 0.f, 0.f);
  }
}

extern "C" void kernel_launch(void* const* d_in, const int* in_sizes, int n_in,
                              void* d_out, int out_size, void* d_ws, size_t ws_size,
                              hipStream_t stream) {
  const float* x = (const float*)d_in[0];
  float* outp = (float*)d_out;
  (void)in_sizes; (void)n_in; (void)out_size; (void)d_ws; (void)ws_size;
  hipLaunchKernelGGL(aa_blur_down, dim3(N_IMG * BANDS * BLOCKS_PER_BAND),
                     dim3(NTHREADS), 0, stream, x, outp);
}